// Round 5
// baseline (79.703 us; speedup 1.0000x reference)
//
#include <hip/hip_runtime.h>

// AdjacencyAttention: B=4096, N=64, D=256, fp32 in/out. Fused, 1 block/batch.
// 128-thread blocks (2 waves), 8 blocks/CU for fine-grained phase interleave.
// P1: lhs/rhs dots (4 thr/row, 2 passes). P2: t=tanh(outer+bs) -> bf16 hi/lo,
// [n][j] XOR-swizzled LDS. P3: s^T = t^T @ Vs^T via mfma_16x16x32_bf16
// (operand-swapped, 3-product hi/lo split), B-frags reused across 2 row-tiles.
// P4: block softmax over 4096, float4 stores.

typedef float f32x4 __attribute__((ext_vector_type(4)));
typedef __bf16 bf16x8 __attribute__((ext_vector_type(8)));

__global__ __launch_bounds__(128, 4) void adjatt_kernel(
    const float* __restrict__ x,   // (B,64,256)
    const float* __restrict__ W1,  // (1,)
    const float* __restrict__ W2,  // (256,1)
    const float* __restrict__ W3,  // (256,)
    const float* __restrict__ bs,  // (1,64,64)
    const float* __restrict__ Vs,  // (64,64)
    float* __restrict__ out)       // (B,64,64)
{
    __shared__ __align__(16) unsigned char tT[16384]; // [0,8K): hi bf16 [n][j] swz; [8K,16K): lo
    __shared__ __align__(16) float lhs[64];
    __shared__ __align__(16) float rhs[64];
    __shared__ float redm[2], reds[2];

    const int tid  = threadIdx.x;
    const int b    = blockIdx.x;
    const int lane = tid & 63;
    const int w    = tid >> 6;       // wave 0/1
    const float W1v = W1[0];

    // ---- Vs fragments for row-blocks rb = 2w + rt, hi/lo split (B operand) ----
    // frag layout: lane l holds M[l&15][8*(l>>4)+e], e=0..7 (k-contiguous)
    bf16x8 Vh[2][2], Vl[2][2];
    #pragma unroll
    for (int rt = 0; rt < 2; ++rt) {
        const int row = 32 * w + 16 * rt + (lane & 15);
        #pragma unroll
        for (int sk = 0; sk < 2; ++sk) {
            const float* vp = Vs + row * 64 + 32 * sk + 8 * (lane >> 4);
            f32x4 f0 = *(const f32x4*)vp;
            f32x4 f1 = *(const f32x4*)(vp + 4);
            #pragma unroll
            for (int e = 0; e < 4; ++e) {
                __bf16 h0 = (__bf16)f0[e];
                Vh[rt][sk][e] = h0;
                Vl[rt][sk][e] = (__bf16)(f0[e] - (float)h0);
                __bf16 h1 = (__bf16)f1[e];
                Vh[rt][sk][e + 4] = h1;
                Vl[rt][sk][e + 4] = (__bf16)(f1[e] - (float)h1);
            }
        }
    }

    // ---- Phase 1: lhs[r] = (x[r,:]·W2)*W1 ; rhs[r] = x[r,:]·W3 (4 thr/row) ----
    {
        const int q  = tid & 3;          // quad slot; lane-quads read 64B contiguous
        const int r0 = tid >> 2;         // 0..31
        #pragma unroll
        for (int pass = 0; pass < 2; ++pass) {
            const int r = 32 * pass + r0;
            const float* xr  = x + (size_t)b * 16384 + r * 256 + q * 4;
            const float* w2p = W2 + q * 4;   // L1-hot (2KB weights)
            const float* w3p = W3 + q * 4;
            float d2 = 0.f, d3 = 0.f;
            #pragma unroll 4
            for (int c = 0; c < 16; ++c) {
                f32x4 xv = *(const f32x4*)(xr + c * 16);
                f32x4 w2 = *(const f32x4*)(w2p + c * 16);
                f32x4 w3 = *(const f32x4*)(w3p + c * 16);
                d2 = fmaf(xv[0], w2[0], d2); d2 = fmaf(xv[1], w2[1], d2);
                d2 = fmaf(xv[2], w2[2], d2); d2 = fmaf(xv[3], w2[3], d2);
                d3 = fmaf(xv[0], w3[0], d3); d3 = fmaf(xv[1], w3[1], d3);
                d3 = fmaf(xv[2], w3[2], d3); d3 = fmaf(xv[3], w3[3], d3);
            }
            d2 += __shfl_xor(d2, 1); d2 += __shfl_xor(d2, 2);
            d3 += __shfl_xor(d3, 1); d3 += __shfl_xor(d3, 2);
            if (q == 0) { lhs[r] = d2 * W1v; rhs[r] = d3; }
        }
    }
    __syncthreads();

    // ---- Phase 2: t[j][n] = tanh(lhs[j]*rhs[n] + bs[j][n]) -> tT[n][j] hi/lo ----
    {
        const int n  = lane;          // t column
        const int j0 = 32 * w;        // this wave covers rows j0..j0+31
        const float rv = rhs[n];
        #pragma unroll
        for (int c = 0; c < 4; ++c) {
            const int jb = j0 + 8 * c;
            f32x4 l0 = *(const f32x4*)&lhs[jb];
            f32x4 l1 = *(const f32x4*)&lhs[jb + 4];
            bf16x8 hi, lo;
            #pragma unroll
            for (int jj = 0; jj < 8; ++jj) {
                const float lj = (jj < 4) ? l0[jj & 3] : l1[jj & 3];
                float z  = fmaf(lj, rv, bs[(jb + jj) * 64 + n]);
                float e2 = __expf(2.f * z);
                float th = 1.f - __fdividef(2.f, e2 + 1.f);  // tanh, saturates at +/-1
                __bf16 h = (__bf16)th;
                hi[jj] = h;
                lo[jj] = (__bf16)(th - (float)h);
            }
            const int off = (n * 128 + jb * 2) ^ ((n & 7) << 4);
            *(bf16x8*)(tT + off)        = hi;
            *(bf16x8*)(tT + 8192 + off) = lo;
        }
    }
    __syncthreads();

    // ---- Phase 3: s^T = t^T @ Vs^T (operand-swapped MFMA) ----
    // acc[rt][ct]: s-rows 32w+16rt.. (N dim via Vs frag), s-cols 16ct.. (M dim)
    f32x4 acc[2][4];
    #pragma unroll
    for (int rt = 0; rt < 2; ++rt)
        #pragma unroll
        for (int ct = 0; ct < 4; ++ct) acc[rt][ct] = (f32x4){0.f, 0.f, 0.f, 0.f};
    #pragma unroll
    for (int ct = 0; ct < 4; ++ct) {
        const int n = 16 * ct + (lane & 15);   // t column read by this lane
        #pragma unroll
        for (int sk = 0; sk < 2; ++sk) {
            const int off = (n * 128 + 64 * sk + 16 * (lane >> 4)) ^ ((n & 7) << 4);
            bf16x8 Th = *(const bf16x8*)(tT + off);
            bf16x8 Tl = *(const bf16x8*)(tT + 8192 + off);
            #pragma unroll
            for (int rt = 0; rt < 2; ++rt) {
                acc[rt][ct] = __builtin_amdgcn_mfma_f32_16x16x32_bf16(Th, Vh[rt][sk], acc[rt][ct], 0, 0, 0);
                acc[rt][ct] = __builtin_amdgcn_mfma_f32_16x16x32_bf16(Tl, Vh[rt][sk], acc[rt][ct], 0, 0, 0);
                acc[rt][ct] = __builtin_amdgcn_mfma_f32_16x16x32_bf16(Th, Vl[rt][sk], acc[rt][ct], 0, 0, 0);
            }
        }
    }

    // ---- Phase 4: softmax over all 4096 scores of this batch ----
    float m = acc[0][0][0];
    #pragma unroll
    for (int rt = 0; rt < 2; ++rt)
        #pragma unroll
        for (int ct = 0; ct < 4; ++ct)
            #pragma unroll
            for (int e = 0; e < 4; ++e) m = fmaxf(m, acc[rt][ct][e]);
    #pragma unroll
    for (int off = 1; off < 64; off <<= 1) m = fmaxf(m, __shfl_xor(m, off));
    if (lane == 0) redm[w] = m;
    __syncthreads();
    const float M = fmaxf(redm[0], redm[1]);

    float ssum = 0.f;
    #pragma unroll
    for (int rt = 0; rt < 2; ++rt)
        #pragma unroll
        for (int ct = 0; ct < 4; ++ct)
            #pragma unroll
            for (int e = 0; e < 4; ++e) {
                acc[rt][ct][e] = __expf(acc[rt][ct][e] - M);
                ssum += acc[rt][ct][e];
            }
    #pragma unroll
    for (int off = 1; off < 64; off <<= 1) ssum += __shfl_xor(ssum, off);
    if (lane == 0) reds[w] = ssum;
    __syncthreads();
    const float inv = __fdividef(1.f, reds[0] + reds[1]);

    // ---- Store: lane holds s[32w+16rt+(l&15)][16ct + 4*(l>>4) .. +3] ----
    #pragma unroll
    for (int rt = 0; rt < 2; ++rt) {
        float* ob = out + (size_t)b * 4096 +
                    (32 * w + 16 * rt + (lane & 15)) * 64 + 4 * (lane >> 4);
        #pragma unroll
        for (int ct = 0; ct < 4; ++ct) {
            f32x4 v = {acc[rt][ct][0] * inv, acc[rt][ct][1] * inv,
                       acc[rt][ct][2] * inv, acc[rt][ct][3] * inv};
            *(f32x4*)(ob + 16 * ct) = v;
        }
    }
}

extern "C" void kernel_launch(void* const* d_in, const int* in_sizes, int n_in,
                              void* d_out, int out_size, void* d_ws, size_t ws_size,
                              hipStream_t stream) {
    const float* x  = (const float*)d_in[0];
    const float* W1 = (const float*)d_in[1];
    const float* W2 = (const float*)d_in[2];
    const float* W3 = (const float*)d_in[3];
    const float* bs = (const float*)d_in[4];
    const float* Vs = (const float*)d_in[5];
    float* out = (float*)d_out;

    const int B = in_sizes[0] / (64 * 256);
    adjatt_kernel<<<dim3(B), dim3(128), 0, stream>>>(x, W1, W2, W3, bs, Vs, out);
}